// Round 4
// baseline (356.809 us; speedup 1.0000x reference)
//
#include <hip/hip_runtime.h>
#include <cstdint>
#include <cstddef>

typedef __bf16 bf16;
typedef __bf16 bf16x8 __attribute__((ext_vector_type(8)));
typedef float  f32x4  __attribute__((ext_vector_type(4)));

#define AS1 __attribute__((address_space(1)))
#define AS3 __attribute__((address_space(3)))

#define B_ 4
#define T_ 2048
#define C_ 1024
#define H_ 8
#define D_ 128
#define WIN_ 1024
#define PS_ 72    // attn P-slab row stride (bf16)
#define TS_ 136   // epilogue tile row stride (bf16): 17 chunks (odd) -> uniform banks

// -------------------------------------------------------------------------
// f32 -> bf16 conversions
// -------------------------------------------------------------------------
__global__ void cvt_kernel(const float* __restrict__ src, bf16* __restrict__ dst, int n) {
  int i = (blockIdx.x * 256 + threadIdx.x) * 8;
  if (i >= n) return;
  float4 a = *(const float4*)(src + i);
  float4 b = *(const float4*)(src + i + 4);
  bf16x8 o;
  o[0] = (bf16)a.x; o[1] = (bf16)a.y; o[2] = (bf16)a.z; o[3] = (bf16)a.w;
  o[4] = (bf16)b.x; o[5] = (bf16)b.y; o[6] = (bf16)b.z; o[7] = (bf16)b.w;
  *(bf16x8*)(dst + i) = o;
}

__global__ void cvt_w4(const float* __restrict__ w0, const float* __restrict__ w1,
                       const float* __restrict__ w2, const float* __restrict__ w3,
                       bf16* __restrict__ dst) {
  const int z = blockIdx.y;
  const float* src = (z == 0) ? w0 : (z == 1) ? w1 : (z == 2) ? w2 : w3;
  int i = (blockIdx.x * 256 + threadIdx.x) * 8;
  float4 a = *(const float4*)(src + i);
  float4 b = *(const float4*)(src + i + 4);
  bf16x8 o;
  o[0] = (bf16)a.x; o[1] = (bf16)a.y; o[2] = (bf16)a.z; o[3] = (bf16)a.w;
  o[4] = (bf16)b.x; o[5] = (bf16)b.y; o[6] = (bf16)b.z; o[7] = (bf16)b.w;
  *(bf16x8*)(dst + (size_t)z * (C_ * C_) + i) = o;
}

// -------------------------------------------------------------------------
// NT-GEMM K-loop core (m97 + XOR chunk swizzle, conflict-free; verified R3)
// -------------------------------------------------------------------------
__device__ __forceinline__ void gemm_tile_compute(
    const bf16* __restrict__ A, const bf16* __restrict__ W,
    bf16* As, bf16* Bs, int m0, int n0, f32x4 acc[4][4])
{
  const int tid  = threadIdx.x;
  const int w    = tid >> 6;
  const int l    = tid & 63;
  const int quad = l >> 4;
  const int arow = l & 15;
  const int lrow = tid >> 3;
  const int lcol = ((tid & 7) ^ (lrow & 7)) * 8;
  const int wm = w >> 1, wn = w & 1;
  const int sw = (arow & 7);

  for (int kt = 0; kt < C_; kt += 64) {
    __syncthreads();
#pragma unroll
    for (int i = 0; i < 4; i++) {
      const bf16* ga = A + (size_t)(m0 + i * 32 + lrow) * C_ + kt + lcol;
      __builtin_amdgcn_global_load_lds((AS1 unsigned int*)ga,
          (AS3 unsigned int*)(As + i * 2048 + w * 512), 16, 0, 0);
      const bf16* gb = W + (size_t)(n0 + i * 32 + lrow) * C_ + kt + lcol;
      __builtin_amdgcn_global_load_lds((AS1 unsigned int*)gb,
          (AS3 unsigned int*)(Bs + i * 2048 + w * 512), 16, 0, 0);
    }
    __syncthreads();

#pragma unroll
    for (int ks = 0; ks < 2; ks++) {
      const int ch = ((ks * 4 + quad) ^ sw) * 8;
      bf16x8 af[4], bfr[4];
#pragma unroll
      for (int mt = 0; mt < 4; mt++)
        af[mt] = *(const bf16x8*)(As + (wm * 64 + mt * 16 + arow) * 64 + ch);
#pragma unroll
      for (int nt = 0; nt < 4; nt++)
        bfr[nt] = *(const bf16x8*)(Bs + (wn * 64 + nt * 16 + arow) * 64 + ch);
#pragma unroll
      for (int mt = 0; mt < 4; mt++)
#pragma unroll
        for (int nt = 0; nt < 4; nt++)
          acc[mt][nt] = __builtin_amdgcn_mfma_f32_16x16x32_bf16(af[mt], bfr[nt], acc[mt][nt], 0, 0, 0);
    }
  }
}

// -------------------------------------------------------------------------
// QKV GEMM with fused per-z epilogues. 1D grid 1536, XCD-aware decode:
// each XCD owns 8 m-tiles x {3 z x 8 n} -> x-tile fetched ~once per m-tile.
// n-tile(128) == one head, so rope/rms (q,k) and gate+transpose (v) are
// block-local. Epilogue tile in LDS, stride 136 (odd chunk count).
// -------------------------------------------------------------------------
__global__ __launch_bounds__(256) void gemm_qkv(
    const bf16* __restrict__ xb, const bf16* __restrict__ wb,
    const float* __restrict__ x, const float* __restrict__ ve,
    const float* __restrict__ cosb, const float* __restrict__ sinb,
    const float* __restrict__ wg,
    bf16* __restrict__ qh, bf16* __restrict__ kh, bf16* __restrict__ vt)
{
  __shared__ bf16 TileS[128 * TS_];   // 34816 B; aliases As/Bs during K-loop
  __shared__ float Gs[128];
  bf16* As = TileS;
  bf16* Bs = TileS + 8192;

  const int bid = blockIdx.x;
  const int xcd = bid & 7, local = bid >> 3;
  const int mi = local / 24, rem = local % 24;
  const int z = rem >> 3, n = rem & 7;
  const int m = mi * 8 + xcd;
  const int m0 = m * 128, n0 = n * 128, h = n;

  const bf16* W = wb + (size_t)z * (C_ * C_);
  f32x4 acc[4][4];
#pragma unroll
  for (int i = 0; i < 4; i++)
#pragma unroll
    for (int j = 0; j < 4; j++) acc[i][j] = (f32x4){0.f, 0.f, 0.f, 0.f};

  gemm_tile_compute(xb, W, As, Bs, m0, n0, acc);

  const int tid = threadIdx.x, w = tid >> 6, l = tid & 63;
  const int quad = l >> 4, l15 = l & 15, wm = w >> 1, wn = w & 1;
  const int bb = m0 >> 11;            // batch (tile never spans batches)
  const int tbase = m0 & 2047;

  if (z == 2) {
    // ---- per-row gate: g = 2*sigmoid(x[b,t,:32] . Wg[h]) ----
    {
      const int r = tid >> 1, p = tid & 1;
      const float* xr = x + ((size_t)(bb * T_ + tbase + r)) * C_ + p * 16;
      const float* wgr = wg + h * 32 + p * 16;
      float partial = 0.f;
#pragma unroll
      for (int j = 0; j < 16; j++) partial += xr[j] * wgr[j];
      partial += __shfl_xor(partial, 1);
      if (p == 0) Gs[r] = 2.0f / (1.0f + __expf(-partial));
    }
    __syncthreads();   // Gs ready; K-loop LDS reads done across waves

    // ---- acc + g*ve -> LDS transposed [d][t] ----
#pragma unroll
    for (int mt = 0; mt < 4; mt++)
#pragma unroll
      for (int nt = 0; nt < 4; nt++) {
        const int col = wn * 64 + nt * 16 + l15;     // d
#pragma unroll
        for (int r = 0; r < 4; r++) {
          const int rowl = wm * 64 + mt * 16 + quad * 4 + r;
          const float vv = acc[mt][nt][r]
              + Gs[rowl] * ve[((size_t)(bb * T_ + tbase + rowl)) * C_ + h * D_ + col];
          TileS[col * TS_ + rowl] = (bf16)vv;
        }
      }
    __syncthreads();

    // ---- coalesced store: vt (B,H,D,T) ----
    const int dr = tid >> 1, p = tid & 1;
    bf16* outp = vt + (((size_t)(bb * H_ + h)) * D_ + dr) * T_ + tbase + p * 64;
#pragma unroll
    for (int c = 0; c < 8; c++)
      *(bf16x8*)(outp + c * 8) = *(const bf16x8*)(TileS + dr * TS_ + p * 64 + c * 8);
  } else {
    __syncthreads();   // K-loop LDS reads done across waves
    // ---- acc -> LDS row-major [t][d] ----
#pragma unroll
    for (int mt = 0; mt < 4; mt++)
#pragma unroll
      for (int nt = 0; nt < 4; nt++) {
        const int col = wn * 64 + nt * 16 + l15;
#pragma unroll
        for (int r = 0; r < 4; r++) {
          const int rowl = wm * 64 + mt * 16 + quad * 4 + r;
          TileS[rowl * TS_ + col] = (bf16)acc[mt][nt][r];
        }
      }
    __syncthreads();

    // ---- rope + rmsnorm, two-pass; thread pair (r, p) owns 32 dim-pairs ----
    const int r = tid >> 1, p = tid & 1;
    const int t = tbase + r;
    const float QSC = 0.08838834764831845f * 1.4426950408889634f; // D^-0.5 * log2e
    const float eps = 1.1920929e-07f;
    const float4* cp = (const float4*)(cosb + (size_t)t * 64 + p * 32);
    const float4* sp = (const float4*)(sinb + (size_t)t * 64 + p * 32);
    const bf16* t1 = TileS + r * TS_ + p * 32;
    const bf16* t2 = t1 + 64;

    float ss = 0.f;
#pragma unroll
    for (int c = 0; c < 8; c++) {
      float4 cv = cp[c], sv = sp[c];
      const bf16* a = t1 + c * 4;
      const bf16* bq = t2 + c * 4;
      float x1, x2, o1, o2;
      x1 = (float)a[0]; x2 = (float)bq[0];
      o1 = x1 * cv.x + x2 * sv.x; o2 = x2 * cv.x - x1 * sv.x; ss += o1 * o1 + o2 * o2;
      x1 = (float)a[1]; x2 = (float)bq[1];
      o1 = x1 * cv.y + x2 * sv.y; o2 = x2 * cv.y - x1 * sv.y; ss += o1 * o1 + o2 * o2;
      x1 = (float)a[2]; x2 = (float)bq[2];
      o1 = x1 * cv.z + x2 * sv.z; o2 = x2 * cv.z - x1 * sv.z; ss += o1 * o1 + o2 * o2;
      x1 = (float)a[3]; x2 = (float)bq[3];
      o1 = x1 * cv.w + x2 * sv.w; o2 = x2 * cv.w - x1 * sv.w; ss += o1 * o1 + o2 * o2;
    }
    ss += __shfl_xor(ss, 1);
    const float sc = rsqrtf(ss * (1.0f / 128.0f) + eps) * (z == 0 ? QSC : 1.0f);

    bf16* outp = (z == 0 ? qh : kh) + (((size_t)(bb * H_ + h)) * T_ + t) * D_ + p * 32;
#pragma unroll
    for (int c = 0; c < 4; c++) {
      float4 cv = cp[c * 2], cv2 = cp[c * 2 + 1];
      float4 sv = sp[c * 2], sv2 = sp[c * 2 + 1];
      const bf16* a = t1 + c * 8;
      const bf16* bq = t2 + c * 8;
      bf16x8 o1v, o2v;
      float x1, x2;
      x1 = (float)a[0]; x2 = (float)bq[0];
      o1v[0] = (bf16)((x1 * cv.x + x2 * sv.x) * sc); o2v[0] = (bf16)((x2 * cv.x - x1 * sv.x) * sc);
      x1 = (float)a[1]; x2 = (float)bq[1];
      o1v[1] = (bf16)((x1 * cv.y + x2 * sv.y) * sc); o2v[1] = (bf16)((x2 * cv.y - x1 * sv.y) * sc);
      x1 = (float)a[2]; x2 = (float)bq[2];
      o1v[2] = (bf16)((x1 * cv.z + x2 * sv.z) * sc); o2v[2] = (bf16)((x2 * cv.z - x1 * sv.z) * sc);
      x1 = (float)a[3]; x2 = (float)bq[3];
      o1v[3] = (bf16)((x1 * cv.w + x2 * sv.w) * sc); o2v[3] = (bf16)((x2 * cv.w - x1 * sv.w) * sc);
      x1 = (float)a[4]; x2 = (float)bq[4];
      o1v[4] = (bf16)((x1 * cv2.x + x2 * sv2.x) * sc); o2v[4] = (bf16)((x2 * cv2.x - x1 * sv2.x) * sc);
      x1 = (float)a[5]; x2 = (float)bq[5];
      o1v[5] = (bf16)((x1 * cv2.y + x2 * sv2.y) * sc); o2v[5] = (bf16)((x2 * cv2.y - x1 * sv2.y) * sc);
      x1 = (float)a[6]; x2 = (float)bq[6];
      o1v[6] = (bf16)((x1 * cv2.z + x2 * sv2.z) * sc); o2v[6] = (bf16)((x2 * cv2.z - x1 * sv2.z) * sc);
      x1 = (float)a[7]; x2 = (float)bq[7];
      o1v[7] = (bf16)((x1 * cv2.w + x2 * sv2.w) * sc); o2v[7] = (bf16)((x2 * cv2.w - x1 * sv2.w) * sc);
      *(bf16x8*)(outp + c * 8) = o1v;
      *(bf16x8*)(outp + 64 + c * 8) = o2v;
    }
  }
}

// -------------------------------------------------------------------------
// Proj GEMM, 1D grid 512, XCD-aware (each XCD owns 8 m-tiles).
// -------------------------------------------------------------------------
__global__ __launch_bounds__(256) void gemm_proj(
    const bf16* __restrict__ yb, const bf16* __restrict__ wproj, float* __restrict__ out)
{
  __shared__ bf16 As[128 * 64];
  __shared__ bf16 Bs[128 * 64];
  const int bid = blockIdx.x;
  const int xcd = bid & 7, local = bid >> 3;
  const int m = xcd * 8 + (local >> 3), n = local & 7;
  const int m0 = m * 128, n0 = n * 128;

  f32x4 acc[4][4];
#pragma unroll
  for (int i = 0; i < 4; i++)
#pragma unroll
    for (int j = 0; j < 4; j++) acc[i][j] = (f32x4){0.f, 0.f, 0.f, 0.f};

  gemm_tile_compute(yb, wproj, As, Bs, m0, n0, acc);

  const int tid = threadIdx.x, w = tid >> 6, l = tid & 63;
  const int quad = l >> 4, lc = l & 15, wm = w >> 1, wn = w & 1;
#pragma unroll
  for (int mt = 0; mt < 4; mt++) {
#pragma unroll
    for (int nt = 0; nt < 4; nt++) {
      const int col = n0 + wn * 64 + nt * 16 + lc;
#pragma unroll
      for (int r = 0; r < 4; r++) {
        const int row = m0 + wm * 64 + mt * 16 + quad * 4 + r;
        out[(size_t)row * C_ + col] = acc[mt][nt][r];
      }
    }
  }
}

// -------------------------------------------------------------------------
// MFMA flash attention (R3 structure: fixed-max softmax, XOR-swizzled LDS).
// 1D grid 512, XCD-aware: each XCD owns 4 bh (K/V ~4 MB -> L2-resident).
// -------------------------------------------------------------------------
__global__ __launch_bounds__(256) void attn_mfma(
    const bf16* __restrict__ qh, const bf16* __restrict__ kh,
    const bf16* __restrict__ vt, bf16* __restrict__ yb)
{
  __shared__ bf16 Ks[64 * 128];
  __shared__ bf16 VTs[128 * 64];
  __shared__ bf16 Ps[4 * 32 * PS_];
  const int bid = blockIdx.x;
  const int xcd = bid & 7, local = bid >> 3;
  const int bh = xcd * 4 + (local >> 4);
  const int q0 = (local & 15) * 128;
  const int tid = threadIdx.x;
  const int w = tid >> 6, l = tid & 63;
  const int quad = l >> 4, l15 = l & 15;
  const int sw = l15 & 7;
  const float FMAX = 16.5f;

  bf16x8 qf[2][4];
  const bf16* qbase = qh + ((size_t)bh * T_ + q0 + w * 32 + l15) * D_;
#pragma unroll
  for (int mt = 0; mt < 2; mt++)
#pragma unroll
    for (int dk = 0; dk < 4; dk++)
      qf[mt][dk] = *(const bf16x8*)(qbase + mt * 16 * D_ + dk * 32 + quad * 8);

  f32x4 O[2][8];
  f32x4 lst[2];
#pragma unroll
  for (int mt = 0; mt < 2; mt++) {
    lst[mt] = (f32x4){0.f, 0.f, 0.f, 0.f};
#pragma unroll
    for (int dn = 0; dn < 8; dn++) O[mt][dn] = (f32x4){0.f, 0.f, 0.f, 0.f};
  }

  const int kt_lo = (q0 >= WIN_) ? ((q0 - (WIN_ - 1)) >> 6) : 0;
  const int kt_hi = (q0 + 127) >> 6;
  const bf16* kg = kh + (size_t)bh * T_ * D_;
  const bf16* vg = vt + (size_t)bh * D_ * T_;
  bf16* Pw = Ps + w * 32 * PS_;

  const int krow_s = w * 4 + (l >> 4);
  const int kcol_s = (l15 ^ (krow_s & 7)) * 8;
  const int vrow_s = w * 8 + (l >> 3);
  const int vcol_s = (((l & 7) ^ (vrow_s & 7))) * 8;

  for (int kt = kt_lo; kt <= kt_hi; kt++) {
    const int k0 = kt * 64;
    __syncthreads();
#pragma unroll
    for (int s = 0; s < 4; s++) {
      const bf16* gk = kg + (size_t)(k0 + s * 16 + krow_s) * D_ + kcol_s;
      __builtin_amdgcn_global_load_lds((AS1 unsigned int*)gk,
          (AS3 unsigned int*)(Ks + s * 2048 + w * 512), 16, 0, 0);
      const bf16* gv = vg + (size_t)(s * 32 + vrow_s) * T_ + k0 + vcol_s;
      __builtin_amdgcn_global_load_lds((AS1 unsigned int*)gv,
          (AS3 unsigned int*)(VTs + s * 2048 + w * 512), 16, 0, 0);
    }
    __syncthreads();

    f32x4 sv[2][4];
#pragma unroll
    for (int mt = 0; mt < 2; mt++)
#pragma unroll
      for (int nf = 0; nf < 4; nf++) sv[mt][nf] = (f32x4){0.f, 0.f, 0.f, 0.f};
#pragma unroll
    for (int dk = 0; dk < 4; dk++) {
      const int ch = ((dk * 4 + quad) ^ sw) * 8;
      bf16x8 kf[4];
#pragma unroll
      for (int nf = 0; nf < 4; nf++)
        kf[nf] = *(const bf16x8*)(Ks + (nf * 16 + l15) * 128 + ch);
#pragma unroll
      for (int mt = 0; mt < 2; mt++)
#pragma unroll
        for (int nf = 0; nf < 4; nf++)
          sv[mt][nf] = __builtin_amdgcn_mfma_f32_16x16x32_bf16(qf[mt][dk], kf[nf], sv[mt][nf], 0, 0, 0);
    }

    if (!((k0 + 63 <= q0) && (k0 >= q0 + 128 - WIN_))) {
#pragma unroll
      for (int mt = 0; mt < 2; mt++)
#pragma unroll
        for (int nf = 0; nf < 4; nf++) {
          const int kcol = k0 + nf * 16 + l15;
#pragma unroll
          for (int r = 0; r < 4; r++) {
            const int qrow = q0 + w * 32 + mt * 16 + quad * 4 + r;
            const bool ok = (kcol <= qrow) && (kcol > qrow - WIN_);
            sv[mt][nf][r] = ok ? sv[mt][nf][r] : -3.0e38f;
          }
        }
    }

#pragma unroll
    for (int mt = 0; mt < 2; mt++) {
#pragma unroll
      for (int nf = 0; nf < 4; nf++)
#pragma unroll
        for (int r = 0; r < 4; r++) {
          const float p = __builtin_amdgcn_exp2f(sv[mt][nf][r] - FMAX);
          sv[mt][nf][r] = p;
          lst[mt][r] += p;
        }
#pragma unroll
      for (int nf = 0; nf < 4; nf++)
#pragma unroll
        for (int r = 0; r < 4; r++)
          Pw[(mt * 16 + quad * 4 + r) * PS_ + nf * 16 + l15] = (bf16)sv[mt][nf][r];
    }

    asm volatile("" ::: "memory");

#pragma unroll
    for (int ks = 0; ks < 2; ks++) {
      const int ch = ((ks * 4 + quad) ^ sw) * 8;
      bf16x8 af0 = *(const bf16x8*)(Pw + l15 * PS_ + ks * 32 + quad * 8);
      bf16x8 af1 = *(const bf16x8*)(Pw + (16 + l15) * PS_ + ks * 32 + quad * 8);
#pragma unroll
      for (int dn = 0; dn < 8; dn++) {
        bf16x8 bfv = *(const bf16x8*)(VTs + (dn * 16 + l15) * 64 + ch);
        O[0][dn] = __builtin_amdgcn_mfma_f32_16x16x32_bf16(af0, bfv, O[0][dn], 0, 0, 0);
        O[1][dn] = __builtin_amdgcn_mfma_f32_16x16x32_bf16(af1, bfv, O[1][dn], 0, 0, 0);
      }
    }
  }

#pragma unroll
  for (int mt = 0; mt < 2; mt++)
#pragma unroll
    for (int off = 1; off < 16; off <<= 1)
#pragma unroll
      for (int r = 0; r < 4; r++) lst[mt][r] += __shfl_xor(lst[mt][r], off);

  const int b = bh >> 3, h = bh & 7;
#pragma unroll
  for (int mt = 0; mt < 2; mt++) {
    f32x4 inv;
#pragma unroll
    for (int r = 0; r < 4; r++) inv[r] = 1.0f / lst[mt][r];
#pragma unroll
    for (int dn = 0; dn < 8; dn++)
#pragma unroll
      for (int r = 0; r < 4; r++) {
        const int t = q0 + w * 32 + mt * 16 + quad * 4 + r;
        yb[((size_t)(b * T_ + t)) * C_ + h * D_ + dn * 16 + l15] = (bf16)(O[mt][dn][r] * inv[r]);
      }
  }
}

// -------------------------------------------------------------------------
// Launcher. ws layout (bytes), total 73,400,320:
//   [0,16M)    xb (x bf16)  -- dead after gemm_qkv, reused as yb (attn out)
//   [16M,24M)  wb (4 weights bf16)
//   [24M,40M)  qh   [40M,56M) kh   [56M,72M) vt (B,H,D,T)
// -------------------------------------------------------------------------
extern "C" void kernel_launch(void* const* d_in, const int* in_sizes, int n_in,
                              void* d_out, int out_size, void* d_ws, size_t ws_size,
                              hipStream_t stream) {
  const float* x     = (const float*)d_in[0];
  const float* ve    = (const float*)d_in[1];
  const float* cosb  = (const float*)d_in[2];
  const float* sinb  = (const float*)d_in[3];
  const float* Wq    = (const float*)d_in[4];
  const float* Wk    = (const float*)d_in[5];
  const float* Wv    = (const float*)d_in[6];
  const float* Wproj = (const float*)d_in[7];
  const float* Wg    = (const float*)d_in[8];

  char* ws = (char*)d_ws;
  bf16* xb = (bf16*)ws;
  bf16* wb = (bf16*)(ws + 16777216);
  bf16* qh = (bf16*)(ws + 25165824);
  bf16* kh = (bf16*)(ws + 41943040);
  bf16* vt = (bf16*)(ws + 58720256);
  bf16* yb = xb;   // xb dead after gemm_qkv

  const int NX = B_ * T_ * C_;
  const int NW = C_ * C_;

  cvt_kernel<<<NX / 8 / 256, 256, 0, stream>>>(x, xb, NX);
  cvt_w4<<<dim3(NW / 8 / 256, 4), 256, 0, stream>>>(Wq, Wk, Wv, Wproj, wb);

  gemm_qkv<<<1536, 256, 0, stream>>>(xb, wb, x, ve, cosb, sinb, Wg, qh, kh, vt);
  attn_mfma<<<512, 256, 0, stream>>>(qh, kh, vt, yb);
  gemm_proj<<<512, 256, 0, stream>>>(yb, wb + 3 * NW, (float*)d_out);
}

// Round 5
// 299.218 us; speedup vs baseline: 1.1925x; 1.1925x over previous
//
#include <hip/hip_runtime.h>
#include <cstdint>
#include <cstddef>

typedef __bf16 bf16;
typedef __bf16 bf16x8 __attribute__((ext_vector_type(8)));
typedef float  f32x4  __attribute__((ext_vector_type(4)));

#define AS1 __attribute__((address_space(1)))
#define AS3 __attribute__((address_space(3)))

#define B_ 4
#define T_ 2048
#define C_ 1024
#define H_ 8
#define D_ 128
#define WIN_ 1024
#define PS_ 72    // attn P-slab row stride (bf16)

// -------------------------------------------------------------------------
// f32 -> bf16 conversions
// -------------------------------------------------------------------------
__global__ void cvt_kernel(const float* __restrict__ src, bf16* __restrict__ dst, int n) {
  int i = (blockIdx.x * 256 + threadIdx.x) * 8;
  if (i >= n) return;
  float4 a = *(const float4*)(src + i);
  float4 b = *(const float4*)(src + i + 4);
  bf16x8 o;
  o[0] = (bf16)a.x; o[1] = (bf16)a.y; o[2] = (bf16)a.z; o[3] = (bf16)a.w;
  o[4] = (bf16)b.x; o[5] = (bf16)b.y; o[6] = (bf16)b.z; o[7] = (bf16)b.w;
  *(bf16x8*)(dst + i) = o;
}

__global__ void cvt_w4(const float* __restrict__ w0, const float* __restrict__ w1,
                       const float* __restrict__ w2, const float* __restrict__ w3,
                       bf16* __restrict__ dst) {
  const int z = blockIdx.y;
  const float* src = (z == 0) ? w0 : (z == 1) ? w1 : (z == 2) ? w2 : w3;
  int i = (blockIdx.x * 256 + threadIdx.x) * 8;
  float4 a = *(const float4*)(src + i);
  float4 b = *(const float4*)(src + i + 4);
  bf16x8 o;
  o[0] = (bf16)a.x; o[1] = (bf16)a.y; o[2] = (bf16)a.z; o[3] = (bf16)a.w;
  o[4] = (bf16)b.x; o[5] = (bf16)b.y; o[6] = (bf16)b.z; o[7] = (bf16)b.w;
  *(bf16x8*)(dst + (size_t)z * (C_ * C_) + i) = o;
}

// -------------------------------------------------------------------------
// NT-GEMM K-loop core (m97 + XOR chunk swizzle, conflict-free; R3-proven)
// -------------------------------------------------------------------------
__device__ __forceinline__ void gemm_tile_compute(
    const bf16* __restrict__ A, const bf16* __restrict__ W,
    bf16* As, bf16* Bs, int m0, int n0, f32x4 acc[4][4])
{
  const int tid  = threadIdx.x;
  const int w    = tid >> 6;
  const int l    = tid & 63;
  const int quad = l >> 4;
  const int arow = l & 15;
  const int lrow = tid >> 3;
  const int lcol = ((tid & 7) ^ (lrow & 7)) * 8;
  const int wm = w >> 1, wn = w & 1;
  const int sw = (arow & 7);

  for (int kt = 0; kt < C_; kt += 64) {
    __syncthreads();
#pragma unroll
    for (int i = 0; i < 4; i++) {
      const bf16* ga = A + (size_t)(m0 + i * 32 + lrow) * C_ + kt + lcol;
      __builtin_amdgcn_global_load_lds((AS1 unsigned int*)ga,
          (AS3 unsigned int*)(As + i * 2048 + w * 512), 16, 0, 0);
      const bf16* gb = W + (size_t)(n0 + i * 32 + lrow) * C_ + kt + lcol;
      __builtin_amdgcn_global_load_lds((AS1 unsigned int*)gb,
          (AS3 unsigned int*)(Bs + i * 2048 + w * 512), 16, 0, 0);
    }
    __syncthreads();

#pragma unroll
    for (int ks = 0; ks < 2; ks++) {
      const int ch = ((ks * 4 + quad) ^ sw) * 8;
      bf16x8 af[4], bfr[4];
#pragma unroll
      for (int mt = 0; mt < 4; mt++)
        af[mt] = *(const bf16x8*)(As + (wm * 64 + mt * 16 + arow) * 64 + ch);
#pragma unroll
      for (int nt = 0; nt < 4; nt++)
        bfr[nt] = *(const bf16x8*)(Bs + (wn * 64 + nt * 16 + arow) * 64 + ch);
#pragma unroll
      for (int mt = 0; mt < 4; mt++)
#pragma unroll
        for (int nt = 0; nt < 4; nt++)
          acc[mt][nt] = __builtin_amdgcn_mfma_f32_16x16x32_bf16(af[mt], bfr[nt], acc[mt][nt], 0, 0, 0);
    }
  }
}

// QKV GEMM (R3-exact): z in {0,1,2} selects Wq/Wk/Wv; writes bf16 (B,H,T,D)
__global__ __launch_bounds__(256) void gemm_qkv(
    const bf16* __restrict__ xb, const bf16* __restrict__ wb,
    bf16* __restrict__ qh, bf16* __restrict__ kh, bf16* __restrict__ vh)
{
  __shared__ bf16 As[128 * 64];
  __shared__ bf16 Bs[128 * 64];
  const int z = blockIdx.z;
  const bf16* W = wb + (size_t)z * (C_ * C_);
  bf16* out = (z == 0) ? qh : (z == 1) ? kh : vh;
  const int m0 = blockIdx.y * 128, n0 = blockIdx.x * 128;

  f32x4 acc[4][4];
#pragma unroll
  for (int i = 0; i < 4; i++)
#pragma unroll
    for (int j = 0; j < 4; j++) acc[i][j] = (f32x4){0.f, 0.f, 0.f, 0.f};

  gemm_tile_compute(xb, W, As, Bs, m0, n0, acc);

  const int tid = threadIdx.x, w = tid >> 6, l = tid & 63;
  const int quad = l >> 4, lc = l & 15, wm = w >> 1, wn = w & 1;
#pragma unroll
  for (int mt = 0; mt < 4; mt++) {
#pragma unroll
    for (int nt = 0; nt < 4; nt++) {
      const int col = n0 + wn * 64 + nt * 16 + lc;
      const int h = col >> 7, d = col & 127;
#pragma unroll
      for (int r = 0; r < 4; r++) {
        const int row = m0 + wm * 64 + mt * 16 + quad * 4 + r;
        const int b = row >> 11, t = row & 2047;
        out[(((size_t)(b * H_ + h)) * T_ + t) * D_ + d] = (bf16)acc[mt][nt][r];
      }
    }
  }
}

// Proj GEMM (R3-exact): f32 row-major epilogue into d_out
__global__ __launch_bounds__(256) void gemm_proj(
    const bf16* __restrict__ yb, const bf16* __restrict__ wproj, float* __restrict__ out)
{
  __shared__ bf16 As[128 * 64];
  __shared__ bf16 Bs[128 * 64];
  const int m0 = blockIdx.y * 128, n0 = blockIdx.x * 128;

  f32x4 acc[4][4];
#pragma unroll
  for (int i = 0; i < 4; i++)
#pragma unroll
    for (int j = 0; j < 4; j++) acc[i][j] = (f32x4){0.f, 0.f, 0.f, 0.f};

  gemm_tile_compute(yb, wproj, As, Bs, m0, n0, acc);

  const int tid = threadIdx.x, w = tid >> 6, l = tid & 63;
  const int quad = l >> 4, lc = l & 15, wm = w >> 1, wn = w & 1;
#pragma unroll
  for (int mt = 0; mt < 4; mt++) {
#pragma unroll
    for (int nt = 0; nt < 4; nt++) {
      const int col = n0 + wn * 64 + nt * 16 + lc;
#pragma unroll
      for (int r = 0; r < 4; r++) {
        const int row = m0 + wm * 64 + mt * 16 + quad * 4 + r;
        out[(size_t)row * C_ + col] = acc[mt][nt][r];
      }
    }
  }
}

// -------------------------------------------------------------------------
// Fused rope+rms (q,k in-place) + gate + V transpose -> vt (B,H,D,T).
// Block = 64 t-rows of one (b,h), 256 threads = 4/row (p owns 32 dims).
// V goes through an f32 LDS tile [t][d] stride 129 (conflict-free column
// reads) and is stored transposed, coalesced.
// -------------------------------------------------------------------------
__global__ __launch_bounds__(256) void rope_gate_t(
    bf16* __restrict__ qh, bf16* __restrict__ kh, const bf16* __restrict__ vh,
    const float* __restrict__ x, const float* __restrict__ ve,
    const float* __restrict__ cosb, const float* __restrict__ sinb,
    const float* __restrict__ wg, bf16* __restrict__ vt)
{
  __shared__ float Tile[64 * 129];
  __shared__ float Gs[64];
  const int bh = blockIdx.y;                 // b*H + h
  const int t0 = blockIdx.x * 64;
  const int b = bh >> 3, h = bh & 7;
  const int tid = threadIdx.x;
  const int r = tid >> 2, p = tid & 3;       // row, quarter
  const int t = t0 + r;
  const float eps = 1.1920929e-07f;
  const float QSC = 0.08838834764831845f * 1.4426950408889634f; // D^-0.5 * log2e

  // ---- gate: g = 2*sigmoid(x[b,t,:32] . Wg[h]) (4 threads x 8 elems) ----
  {
    const float* xr = x + ((size_t)(b * T_ + t)) * C_ + p * 8;
    const float* wgr = wg + h * 32 + p * 8;
    float gp = 0.f;
#pragma unroll
    for (int j = 0; j < 8; j++) gp += xr[j] * wgr[j];
    gp += __shfl_xor(gp, 1);
    gp += __shfl_xor(gp, 2);
    if (p == 0) Gs[r] = 2.0f / (1.0f + __expf(-gp));
  }

  // ---- q,k: rope + rmsnorm in place; thread owns dims [p*16,p*16+16) + 64 ----
  const float4* cp = (const float4*)(cosb + (size_t)t * 64 + p * 16);
  const float4* sp = (const float4*)(sinb + (size_t)t * 64 + p * 16);
#pragma unroll
  for (int zz = 0; zz < 2; zz++) {
    bf16* rowp = (zz == 0 ? qh : kh) + ((size_t)bh * T_ + t) * D_ + p * 16;
    bf16x8 a0 = *(const bf16x8*)(rowp);
    bf16x8 a1 = *(const bf16x8*)(rowp + 8);
    bf16x8 b0 = *(const bf16x8*)(rowp + 64);
    bf16x8 b1 = *(const bf16x8*)(rowp + 72);
    float o1[16], o2[16];
    float ss = 0.f;
#pragma unroll
    for (int c = 0; c < 4; c++) {
      float4 cv = cp[c], sv = sp[c];
      float cf[4] = {cv.x, cv.y, cv.z, cv.w};
      float sf[4] = {sv.x, sv.y, sv.z, sv.w};
#pragma unroll
      for (int j = 0; j < 4; j++) {
        const int e = c * 4 + j;
        const float x1 = (float)(e < 8 ? a0[e] : a1[e - 8]);
        const float x2 = (float)(e < 8 ? b0[e] : b1[e - 8]);
        o1[e] = x1 * cf[j] + x2 * sf[j];
        o2[e] = x2 * cf[j] - x1 * sf[j];
        ss += o1[e] * o1[e] + o2[e] * o2[e];
      }
    }
    ss += __shfl_xor(ss, 1);
    ss += __shfl_xor(ss, 2);
    const float sc = rsqrtf(ss * (1.0f / 128.0f) + eps) * (zz == 0 ? QSC : 1.0f);
    bf16x8 w0, w1, w2, w3;
#pragma unroll
    for (int e = 0; e < 8; e++) {
      w0[e] = (bf16)(o1[e] * sc); w1[e] = (bf16)(o1[e + 8] * sc);
      w2[e] = (bf16)(o2[e] * sc); w3[e] = (bf16)(o2[e + 8] * sc);
    }
    *(bf16x8*)(rowp) = w0; *(bf16x8*)(rowp + 8) = w1;
    *(bf16x8*)(rowp + 64) = w2; *(bf16x8*)(rowp + 72) = w3;
  }

  // ---- v: (v + g*ve) -> f32 LDS tile [t][d], stride 129 ----
  __syncthreads();   // Gs ready
  {
    const float g = Gs[r];
    const bf16* vr = vh + ((size_t)bh * T_ + t) * D_ + p * 32;
    const float* ver = ve + ((size_t)(b * T_ + t)) * C_ + h * D_ + p * 32;
    float* tr = Tile + r * 129 + p * 32;
#pragma unroll
    for (int c = 0; c < 4; c++) {
      bf16x8 vv = *(const bf16x8*)(vr + c * 8);
      float4 e0 = *(const float4*)(ver + c * 8);
      float4 e1 = *(const float4*)(ver + c * 8 + 4);
      tr[c * 8 + 0] = (float)vv[0] + g * e0.x;
      tr[c * 8 + 1] = (float)vv[1] + g * e0.y;
      tr[c * 8 + 2] = (float)vv[2] + g * e0.z;
      tr[c * 8 + 3] = (float)vv[3] + g * e0.w;
      tr[c * 8 + 4] = (float)vv[4] + g * e1.x;
      tr[c * 8 + 5] = (float)vv[5] + g * e1.y;
      tr[c * 8 + 6] = (float)vv[6] + g * e1.z;
      tr[c * 8 + 7] = (float)vv[7] + g * e1.w;
    }
  }
  __syncthreads();

  // ---- transposed store: thread (d = tid>>1, half = tid&1) owns 32 t ----
  {
    const int d = tid >> 1, half = tid & 1;
    bf16* outp = vt + (((size_t)bh) * D_ + d) * T_ + t0 + half * 32;
#pragma unroll
    for (int c = 0; c < 4; c++) {
      bf16x8 o;
#pragma unroll
      for (int j = 0; j < 8; j++)
        o[j] = (bf16)Tile[(half * 32 + c * 8 + j) * 129 + d];
      *(bf16x8*)(outp + c * 8) = o;
    }
  }
}

// -------------------------------------------------------------------------
// MFMA flash attention (R4, passed twice): fixed-max softmax, XOR-swizzled
// LDS staging, wave-private P slab. 1D grid 512.
// -------------------------------------------------------------------------
__global__ __launch_bounds__(256) void attn_mfma(
    const bf16* __restrict__ qh, const bf16* __restrict__ kh,
    const bf16* __restrict__ vt, bf16* __restrict__ yb)
{
  __shared__ bf16 Ks[64 * 128];
  __shared__ bf16 VTs[128 * 64];
  __shared__ bf16 Ps[4 * 32 * PS_];
  const int bid = blockIdx.x;
  const int xcd = bid & 7, local = bid >> 3;
  const int bh = xcd * 4 + (local >> 4);
  const int q0 = (local & 15) * 128;
  const int tid = threadIdx.x;
  const int w = tid >> 6, l = tid & 63;
  const int quad = l >> 4, l15 = l & 15;
  const int sw = l15 & 7;
  const float FMAX = 16.5f;

  bf16x8 qf[2][4];
  const bf16* qbase = qh + ((size_t)bh * T_ + q0 + w * 32 + l15) * D_;
#pragma unroll
  for (int mt = 0; mt < 2; mt++)
#pragma unroll
    for (int dk = 0; dk < 4; dk++)
      qf[mt][dk] = *(const bf16x8*)(qbase + mt * 16 * D_ + dk * 32 + quad * 8);

  f32x4 O[2][8];
  f32x4 lst[2];
#pragma unroll
  for (int mt = 0; mt < 2; mt++) {
    lst[mt] = (f32x4){0.f, 0.f, 0.f, 0.f};
#pragma unroll
    for (int dn = 0; dn < 8; dn++) O[mt][dn] = (f32x4){0.f, 0.f, 0.f, 0.f};
  }

  const int kt_lo = (q0 >= WIN_) ? ((q0 - (WIN_ - 1)) >> 6) : 0;
  const int kt_hi = (q0 + 127) >> 6;
  const bf16* kg = kh + (size_t)bh * T_ * D_;
  const bf16* vg = vt + (size_t)bh * D_ * T_;
  bf16* Pw = Ps + w * 32 * PS_;

  const int krow_s = w * 4 + (l >> 4);
  const int kcol_s = (l15 ^ (krow_s & 7)) * 8;
  const int vrow_s = w * 8 + (l >> 3);
  const int vcol_s = (((l & 7) ^ (vrow_s & 7))) * 8;

  for (int kt = kt_lo; kt <= kt_hi; kt++) {
    const int k0 = kt * 64;
    __syncthreads();
#pragma unroll
    for (int s = 0; s < 4; s++) {
      const bf16* gk = kg + (size_t)(k0 + s * 16 + krow_s) * D_ + kcol_s;
      __builtin_amdgcn_global_load_lds((AS1 unsigned int*)gk,
          (AS3 unsigned int*)(Ks + s * 2048 + w * 512), 16, 0, 0);
      const bf16* gv = vg + (size_t)(s * 32 + vrow_s) * T_ + k0 + vcol_s;
      __builtin_amdgcn_global_load_lds((AS1 unsigned int*)gv,
          (AS3 unsigned int*)(VTs + s * 2048 + w * 512), 16, 0, 0);
    }
    __syncthreads();

    f32x4 sv[2][4];
#pragma unroll
    for (int mt = 0; mt < 2; mt++)
#pragma unroll
      for (int nf = 0; nf < 4; nf++) sv[mt][nf] = (f32x4){0.f, 0.f, 0.f, 0.f};
#pragma unroll
    for (int dk = 0; dk < 4; dk++) {
      const int ch = ((dk * 4 + quad) ^ sw) * 8;
      bf16x8 kf[4];
#pragma unroll
      for (int nf = 0; nf < 4; nf++)
        kf[nf] = *(const bf16x8*)(Ks + (nf * 16 + l15) * 128 + ch);
#pragma unroll
      for (int mt = 0; mt < 2; mt++)
#pragma unroll
        for (int nf = 0; nf < 4; nf++)
          sv[mt][nf] = __builtin_amdgcn_mfma_f32_16x16x32_bf16(qf[mt][dk], kf[nf], sv[mt][nf], 0, 0, 0);
    }

    if (!((k0 + 63 <= q0) && (k0 >= q0 + 128 - WIN_))) {
#pragma unroll
      for (int mt = 0; mt < 2; mt++)
#pragma unroll
        for (int nf = 0; nf < 4; nf++) {
          const int kcol = k0 + nf * 16 + l15;
#pragma unroll
          for (int r = 0; r < 4; r++) {
            const int qrow = q0 + w * 32 + mt * 16 + quad * 4 + r;
            const bool ok = (kcol <= qrow) && (kcol > qrow - WIN_);
            sv[mt][nf][r] = ok ? sv[mt][nf][r] : -3.0e38f;
          }
        }
    }

#pragma unroll
    for (int mt = 0; mt < 2; mt++) {
#pragma unroll
      for (int nf = 0; nf < 4; nf++)
#pragma unroll
        for (int r = 0; r < 4; r++) {
          const float p = __builtin_amdgcn_exp2f(sv[mt][nf][r] - FMAX);
          sv[mt][nf][r] = p;
          lst[mt][r] += p;
        }
#pragma unroll
      for (int nf = 0; nf < 4; nf++)
#pragma unroll
        for (int r = 0; r < 4; r++)
          Pw[(mt * 16 + quad * 4 + r) * PS_ + nf * 16 + l15] = (bf16)sv[mt][nf][r];
    }

    asm volatile("" ::: "memory");

#pragma unroll
    for (int ks = 0; ks < 2; ks++) {
      const int ch = ((ks * 4 + quad) ^ sw) * 8;
      bf16x8 af0 = *(const bf16x8*)(Pw + l15 * PS_ + ks * 32 + quad * 8);
      bf16x8 af1 = *(const bf16x8*)(Pw + (16 + l15) * PS_ + ks * 32 + quad * 8);
#pragma unroll
      for (int dn = 0; dn < 8; dn++) {
        bf16x8 bfv = *(const bf16x8*)(VTs + (dn * 16 + l15) * 64 + ch);
        O[0][dn] = __builtin_amdgcn_mfma_f32_16x16x32_bf16(af0, bfv, O[0][dn], 0, 0, 0);
        O[1][dn] = __builtin_amdgcn_mfma_f32_16x16x32_bf16(af1, bfv, O[1][dn], 0, 0, 0);
      }
    }
  }

#pragma unroll
  for (int mt = 0; mt < 2; mt++)
#pragma unroll
    for (int off = 1; off < 16; off <<= 1)
#pragma unroll
      for (int r = 0; r < 4; r++) lst[mt][r] += __shfl_xor(lst[mt][r], off);

  const int b = bh >> 3, h = bh & 7;
#pragma unroll
  for (int mt = 0; mt < 2; mt++) {
    f32x4 inv;
#pragma unroll
    for (int r = 0; r < 4; r++) inv[r] = 1.0f / lst[mt][r];
#pragma unroll
    for (int dn = 0; dn < 8; dn++)
#pragma unroll
      for (int r = 0; r < 4; r++) {
        const int t = q0 + w * 32 + mt * 16 + quad * 4 + r;
        yb[((size_t)(b * T_ + t)) * C_ + h * D_ + dn * 16 + l15] = (bf16)(O[mt][dn][r] * inv[r]);
      }
  }
}

// -------------------------------------------------------------------------
// Launcher. ws layout (bytes), total 73,400,320:
//   [0,16M)    xb (x bf16)  -- dead after gemm_qkv, reused as vt
//   [16M,24M)  wb (4 weights bf16)
//   [24M,40M)  qh   [40M,56M) kh
//   [56M,72M)  vh -- dead after rope_gate_t, reused as yb (attn out)
// -------------------------------------------------------------------------
extern "C" void kernel_launch(void* const* d_in, const int* in_sizes, int n_in,
                              void* d_out, int out_size, void* d_ws, size_t ws_size,
                              hipStream_t stream) {
  const float* x     = (const float*)d_in[0];
  const float* ve    = (const float*)d_in[1];
  const float* cosb  = (const float*)d_in[2];
  const float* sinb  = (const float*)d_in[3];
  const float* Wq    = (const float*)d_in[4];
  const float* Wk    = (const float*)d_in[5];
  const float* Wv    = (const float*)d_in[6];
  const float* Wproj = (const float*)d_in[7];
  const float* Wg    = (const float*)d_in[8];

  char* ws = (char*)d_ws;
  bf16* xb = (bf16*)ws;
  bf16* wb = (bf16*)(ws + 16777216);
  bf16* qh = (bf16*)(ws + 25165824);
  bf16* kh = (bf16*)(ws + 41943040);
  bf16* vh = (bf16*)(ws + 58720256);
  bf16* vt = xb;   // xb dead after gemm_qkv
  bf16* yb = vh;   // vh dead after rope_gate_t

  const int NX = B_ * T_ * C_;
  const int NW = C_ * C_;

  cvt_kernel<<<NX / 8 / 256, 256, 0, stream>>>(x, xb, NX);
  cvt_w4<<<dim3(NW / 8 / 256, 4), 256, 0, stream>>>(Wq, Wk, Wv, Wproj, wb);

  gemm_qkv<<<dim3(C_ / 128, (B_ * T_) / 128, 3), 256, 0, stream>>>(xb, wb, qh, kh, vh);
  rope_gate_t<<<dim3(T_ / 64, B_ * H_), 256, 0, stream>>>(qh, kh, vh, x, ve, cosb, sinb, Wg, vt);
  attn_mfma<<<512, 256, 0, stream>>>(qh, kh, vt, yb);
  gemm_proj<<<dim3(C_ / 128, (B_ * T_) / 128), 256, 0, stream>>>(yb, wb + 3 * NW, (float*)d_out);
}